// Round 1
// baseline (612.678 us; speedup 1.0000x reference)
//
#include <hip/hip_runtime.h>
#include <cmath>

// Problem constants (match reference setup_inputs)
constexpr int NN    = 2048;   // neurons
constexpr int NOUT  = 35;     // outputs
constexpr int BATCH = 64;     // batch
constexpr int TCCH  = 8;      // number of t-chunks (parallelism over time)
constexpr int KTRUNC = 256;   // truncated time horizon: tail mass <= e^-25.6 ~ 7.5e-12

// ---------------------------------------------------------------------------
// Kernel A: partial weighted temporal reduction.
//   partial[tc][b][n] = sum_{t in chunk tc} spikes[b][t][n] * decay[t]
// Grid: (BATCH, NN/1024, TCCH), block 256 threads, float4 per thread.
// Fully coalesced: lane i reads 16B at n0 + 16*i, 1024 consecutive floats/block.
// ---------------------------------------------------------------------------
__global__ __launch_bounds__(256) void rate_partial_kernel(
    const float* __restrict__ spikes, float* __restrict__ partial,
    int T, int K, int tchunk, float inv_sum)
{
    const int b   = blockIdx.x;
    const int nc  = blockIdx.y;
    const int tc  = blockIdx.z;
    const int tid = threadIdx.x;
    const int n0  = nc * 1024 + tid * 4;

    const float4* __restrict__ src =
        reinterpret_cast<const float4*>(spikes + (size_t)b * T * NN + n0);

    const int t0 = tc * tchunk;
    int t1 = t0 + tchunk;
    if (t1 > K) t1 = K;

    float ax = 0.f, ay = 0.f, az = 0.f, aw = 0.f;
#pragma unroll 4
    for (int t = t0; t < t1; ++t) {
        const float w = __expf((float)t * -0.1f) * inv_sum;
        const float4 v = src[(size_t)t * (NN / 4)];
        ax = fmaf(v.x, w, ax);
        ay = fmaf(v.y, w, ay);
        az = fmaf(v.z, w, az);
        aw = fmaf(v.w, w, aw);
    }
    *reinterpret_cast<float4*>(partial + ((size_t)tc * BATCH + b) * NN + n0) =
        make_float4(ax, ay, az, aw);
}

// ---------------------------------------------------------------------------
// Kernel B: sum partials -> firing rates (registers), then 35-way readout.
// One block per batch row; 256 threads; each thread owns 8 consecutive n.
// W row reads are coalesced float4; W (287 KB) is L2/L3 resident across blocks.
// ---------------------------------------------------------------------------
__global__ __launch_bounds__(256) void readout_kernel(
    const float* __restrict__ partial, const float* __restrict__ W,
    const float* __restrict__ bias, float* __restrict__ out)
{
    const int b   = blockIdx.x;
    const int tid = threadIdx.x;
    const int n0  = tid * 8;

    float fr[8];
#pragma unroll
    for (int j = 0; j < 8; ++j) fr[j] = 0.f;

#pragma unroll
    for (int tc = 0; tc < TCCH; ++tc) {
        const float4* p = reinterpret_cast<const float4*>(
            partial + ((size_t)tc * BATCH + b) * NN + n0);
        const float4 v0 = p[0];
        const float4 v1 = p[1];
        fr[0] += v0.x; fr[1] += v0.y; fr[2] += v0.z; fr[3] += v0.w;
        fr[4] += v1.x; fr[5] += v1.y; fr[6] += v1.z; fr[7] += v1.w;
    }

    __shared__ float red[4];
    const int lane = tid & 63;
    const int wave = tid >> 6;

    for (int o = 0; o < NOUT; ++o) {
        const float4* wp = reinterpret_cast<const float4*>(W + (size_t)o * NN + n0);
        const float4 w0 = wp[0];
        const float4 w1 = wp[1];
        float s = fr[0] * w0.x + fr[1] * w0.y + fr[2] * w0.z + fr[3] * w0.w
                + fr[4] * w1.x + fr[5] * w1.y + fr[6] * w1.z + fr[7] * w1.w;
#pragma unroll
        for (int off = 32; off > 0; off >>= 1)
            s += __shfl_down(s, off, 64);
        if (lane == 0) red[wave] = s;
        __syncthreads();
        if (tid == 0)
            out[b * NOUT + o] = red[0] + red[1] + red[2] + red[3] + bias[o];
        __syncthreads();
    }
}

extern "C" void kernel_launch(void* const* d_in, const int* in_sizes, int n_in,
                              void* d_out, int out_size, void* d_ws, size_t ws_size,
                              hipStream_t stream) {
    const float* spikes = (const float*)d_in[0];
    const float* W      = (const float*)d_in[1];
    const float* bias   = (const float*)d_in[2];
    float* out          = (float*)d_out;

    const int T = in_sizes[0] / (BATCH * NN);   // 1000
    int K = KTRUNC < T ? KTRUNC : T;
    const int tchunk = (K + TCCH - 1) / TCCH;   // 32

    // Normalization: reference divides by sum_{t<T} exp(-t/10) (f32 sum of f32
    // exps; f64 host sum differs by <1e-8 relative — within tolerance).
    double s = 0.0;
    for (int t = 0; t < T; ++t) s += exp(-(double)t / 10.0);
    const float inv_sum = (float)(1.0 / s);

    float* partial = (float*)d_ws;  // TCCH*BATCH*NN*4 = 4 MB, fully overwritten

    dim3 gridA(BATCH, NN / 1024, TCCH);
    rate_partial_kernel<<<gridA, 256, 0, stream>>>(spikes, partial, T, K, tchunk, inv_sum);

    readout_kernel<<<BATCH, 256, 0, stream>>>(partial, W, bias, out);
}

// Round 2
// 592.582 us; speedup vs baseline: 1.0339x; 1.0339x over previous
//
#include <hip/hip_runtime.h>
#include <cmath>

// Problem constants (match reference setup_inputs)
constexpr int NN    = 2048;   // neurons
constexpr int NOUT  = 35;     // outputs
constexpr int BATCH = 64;     // batch
constexpr int TCCH  = 8;      // t-chunks (parallelism over time)
// Truncated horizon: normalized tail mass at t>=192 is e^-19.2/(1-e^-0.1)/sum
// ~= 4.6e-9 -> worst-case output error ~1e-7 (below f32 reduction noise).
constexpr int KTRUNC = 192;

// ---------------------------------------------------------------------------
// Kernel A: partial weighted temporal reduction.
//   partial[tc][b][n] = sum_{t in chunk tc} spikes[b][t][n] * decay[t]
// Grid: (BATCH, NN/1024, TCCH), block 256, float4/thread. Static trip count
// (TCHUNK=24) so the compiler software-pipelines the loads.
// ---------------------------------------------------------------------------
template <int TCHUNK>
__global__ __launch_bounds__(256) void rate_partial_kernel(
    const float* __restrict__ spikes, float* __restrict__ partial,
    int T, float inv_sum)
{
    const int b   = blockIdx.x;
    const int nc  = blockIdx.y;
    const int tc  = blockIdx.z;
    const int tid = threadIdx.x;
    const int n0  = nc * 1024 + tid * 4;

    const float4* __restrict__ src =
        reinterpret_cast<const float4*>(spikes + (size_t)b * T * NN + n0);

    const int t0 = tc * TCHUNK;
    float ax = 0.f, ay = 0.f, az = 0.f, aw = 0.f;
#pragma unroll 8
    for (int i = 0; i < TCHUNK; ++i) {
        const int t = t0 + i;
        const float w = __expf((float)t * -0.1f) * inv_sum;
        const float4 v = src[(size_t)t * (NN / 4)];
        ax = fmaf(v.x, w, ax);
        ay = fmaf(v.y, w, ay);
        az = fmaf(v.z, w, az);
        aw = fmaf(v.w, w, aw);
    }
    *reinterpret_cast<float4*>(partial + ((size_t)tc * BATCH + b) * NN + n0) =
        make_float4(ax, ay, az, aw);
}

// Dynamic fallback (only used if T != 1000-style shape assumptions break).
__global__ __launch_bounds__(256) void rate_partial_kernel_dyn(
    const float* __restrict__ spikes, float* __restrict__ partial,
    int T, int K, int tchunk, float inv_sum)
{
    const int b   = blockIdx.x;
    const int nc  = blockIdx.y;
    const int tc  = blockIdx.z;
    const int tid = threadIdx.x;
    const int n0  = nc * 1024 + tid * 4;

    const float4* __restrict__ src =
        reinterpret_cast<const float4*>(spikes + (size_t)b * T * NN + n0);

    const int t0 = tc * tchunk;
    int t1 = t0 + tchunk;
    if (t1 > K) t1 = K;

    float ax = 0.f, ay = 0.f, az = 0.f, aw = 0.f;
#pragma unroll 4
    for (int t = t0; t < t1; ++t) {
        const float w = __expf((float)t * -0.1f) * inv_sum;
        const float4 v = src[(size_t)t * (NN / 4)];
        ax = fmaf(v.x, w, ax);
        ay = fmaf(v.y, w, ay);
        az = fmaf(v.z, w, az);
        aw = fmaf(v.w, w, aw);
    }
    *reinterpret_cast<float4*>(partial + ((size_t)tc * BATCH + b) * NN + n0) =
        make_float4(ax, ay, az, aw);
}

// ---------------------------------------------------------------------------
// Kernel B: sum partials -> firing rates in LDS, then 35-way readout with
// outputs distributed across the 4 waves (each wave owns ~9 outputs).
// LDS access sfr[j*64+lane]: bank = lane%32, 2 lanes/bank -> conflict-free.
// ---------------------------------------------------------------------------
__global__ __launch_bounds__(256) void readout_kernel(
    const float* __restrict__ partial, const float* __restrict__ W,
    const float* __restrict__ bias, float* __restrict__ out)
{
    __shared__ float sfr[NN];  // 8 KB
    const int b   = blockIdx.x;
    const int tid = threadIdx.x;
    const int n0  = tid * 8;

    float fr[8];
#pragma unroll
    for (int j = 0; j < 8; ++j) fr[j] = 0.f;

#pragma unroll
    for (int tc = 0; tc < TCCH; ++tc) {
        const float4* p = reinterpret_cast<const float4*>(
            partial + ((size_t)tc * BATCH + b) * NN + n0);
        const float4 v0 = p[0];
        const float4 v1 = p[1];
        fr[0] += v0.x; fr[1] += v0.y; fr[2] += v0.z; fr[3] += v0.w;
        fr[4] += v1.x; fr[5] += v1.y; fr[6] += v1.z; fr[7] += v1.w;
    }
#pragma unroll
    for (int j = 0; j < 8; ++j) sfr[n0 + j] = fr[j];
    __syncthreads();

    const int lane = tid & 63;
    const int wave = tid >> 6;

    for (int o = wave; o < NOUT; o += 4) {
        const float* wrow = W + (size_t)o * NN;
        float s = 0.f;
#pragma unroll 8
        for (int j = 0; j < NN / 64; ++j)
            s = fmaf(sfr[j * 64 + lane], wrow[j * 64 + lane], s);
#pragma unroll
        for (int off = 32; off > 0; off >>= 1)
            s += __shfl_down(s, off, 64);
        if (lane == 0) out[b * NOUT + o] = s + bias[o];
    }
}

extern "C" void kernel_launch(void* const* d_in, const int* in_sizes, int n_in,
                              void* d_out, int out_size, void* d_ws, size_t ws_size,
                              hipStream_t stream) {
    const float* spikes = (const float*)d_in[0];
    const float* W      = (const float*)d_in[1];
    const float* bias   = (const float*)d_in[2];
    float* out          = (float*)d_out;

    const int T = in_sizes[0] / (BATCH * NN);   // 1000

    // Normalization: reference divides by sum_{t<T} exp(-t/10).
    double s = 0.0;
    for (int t = 0; t < T; ++t) s += exp(-(double)t / 10.0);
    const float inv_sum = (float)(1.0 / s);

    float* partial = (float*)d_ws;  // TCCH*BATCH*NN*4 = 4 MB, fully overwritten

    dim3 gridA(BATCH, NN / 1024, TCCH);
    if (T >= KTRUNC) {
        // Static path: K=192, tchunk=24.
        rate_partial_kernel<KTRUNC / TCCH><<<gridA, 256, 0, stream>>>(
            spikes, partial, T, inv_sum);
    } else {
        const int K = T;
        const int tchunk = (K + TCCH - 1) / TCCH;
        rate_partial_kernel_dyn<<<gridA, 256, 0, stream>>>(
            spikes, partial, T, K, tchunk, inv_sum);
    }

    readout_kernel<<<BATCH, 256, 0, stream>>>(partial, W, bias, out);
}